// Round 11
// baseline (233.687 us; speedup 1.0000x reference)
//
#include <hip/hip_runtime.h>
#include <hip/hip_bf16.h>
#include <math.h>

#define B_ 8
#define S_ 1024
#define E_ 768
#define H_ 12
#define P_ 64

typedef __attribute__((ext_vector_type(8))) short bf16x8;
typedef __attribute__((ext_vector_type(4))) float f32x4;

__device__ __forceinline__ short f2bf(float f) {
    union { float f; unsigned u; } v; v.f = f;
    unsigned r = v.u + 0x7FFFu + ((v.u >> 16) & 1u);  // round-to-nearest-even
    return (short)(r >> 16);
}

// HW bf16 convert (compiler emits v_cvt path; m240: beats hand asm). RNE.
__device__ __forceinline__ unsigned f2bf_u(float f) {
    union { __hip_bfloat16 h; unsigned short s; } cv;
    cv.h = __float2bfloat16(f);
    return (unsigned)cv.s;
}
__device__ __forceinline__ short f2bf_hw(float f) {
    return (short)f2bf_u(f);
}

// pack 8 fp32 -> 8 bf16 in a uint4 (element i at short lane i)
__device__ __forceinline__ uint4 pack8(float4 a, float4 b) {
    uint4 u;
    u.x = f2bf_u(a.x) | (f2bf_u(a.y) << 16);
    u.y = f2bf_u(a.z) | (f2bf_u(a.w) << 16);
    u.z = f2bf_u(b.x) | (f2bf_u(b.y) << 16);
    u.w = f2bf_u(b.z) | (f2bf_u(b.w) << 16);
    return u;
}

// ---------------------------------------------------------------------------
// Preprocessing, transposes ONLY (x and q_heads converts are fused into the
// GEMM A-staging now). Blocks: [0,144) kproj^T ; [144,288) vproj^T ;
// [288,432) lifting^T.
// ---------------------------------------------------------------------------
__device__ __forceinline__ void conv_T_body(
    const float* __restrict__ src0, short* __restrict__ dst0, int R, int C,
    int bx, int by, int bz, short (*T)[72])
{
    const int t = threadIdx.x;
    const int r0 = bx * 64, c0 = by * 64;
    const size_t bo = (size_t)bz * R * C;
    const float* src = src0 + bo;
    short* dst = dst0 + bo;
#pragma unroll
    for (int i = 0; i < 4; ++i) {
        int id = i * 256 + t;
        int r = id >> 4, c4 = id & 15;
        float4 f = *(const float4*)(src + (size_t)(r0 + r) * C + c0 + c4 * 4);
        T[c4 * 4 + 0][r] = f2bf(f.x);
        T[c4 * 4 + 1][r] = f2bf(f.y);
        T[c4 * 4 + 2][r] = f2bf(f.z);
        T[c4 * 4 + 3][r] = f2bf(f.w);
    }
    __syncthreads();
#pragma unroll
    for (int i = 0; i < 2; ++i) {
        int id = i * 256 + t;
        int cc = id >> 3, r8 = id & 7;
        *(uint4*)(dst + (size_t)(c0 + cc) * R + r0 + r8 * 8) = *(const uint4*)&T[cc][r8 * 8];
    }
}

__global__ __launch_bounds__(256) void conv_fused(
    const float* __restrict__ kproj, const float* __restrict__ vproj,
    const float* __restrict__ lifting,
    short* __restrict__ kTw, short* __restrict__ vTw, short* __restrict__ liftT)
{
    __shared__ short T[64][72];
    const int bid = (int)blockIdx.x;
    if (bid < 144) {
        conv_T_body(kproj, kTw, E_, P_, bid % 12, 0, bid / 12, T);
    } else if (bid < 288) {
        int r = bid - 144;
        conv_T_body(vproj, vTw, E_, P_, r % 12, 0, r / 12, T);
    } else {
        int r = bid - 288;                         // lifting: grid (12,12,1)
        conv_T_body(lifting, liftT, E_, E_, r % 12, r / 12, 0, T);
    }
}

// ---------------------------------------------------------------------------
// 8-wave MFMA GEMM core: C(128x128) = A(128xK) @ [B0;B1](128xK)^T.
// T14 register-prefetch double-buffer, scalarized staging (R9 proven).
// AF32: A is fp32; converted to bf16 during the regs->LDS write (fuses the
// former conv_bf16 pass into the staging; same RNE convert -> same numerics).
// ---------------------------------------------------------------------------
template<bool AF32>
__device__ __forceinline__ void mfma_gemm_128x128(
    const void* __restrict__ Ap, int lda,
    const short* __restrict__ B0, const short* __restrict__ B1, int ldb, int K,
    short (*As)[72], short (*Bs)[72], f32x4 (&acc)[2][4])
{
    const int tid = threadIdx.x;
    const int w = tid >> 6, lane = tid & 63, quad = lane >> 4, ln = lane & 15;
    const int wm = w & 3, wn = w >> 2;

    const int r = tid >> 3, c8 = (tid & 7) * 8;
    const float* fA0 = (const float*)Ap + (size_t)r * lda + c8;
    const float* fA1 = (const float*)Ap + (size_t)(r + 64) * lda + c8;
    const short* sA0 = (const short*)Ap + (size_t)r * lda + c8;
    const short* sA1 = (const short*)Ap + (size_t)(r + 64) * lda + c8;
    const short* sB0 = B0 + (size_t)r * ldb + c8;
    const short* sB1 = B1 + (size_t)r * ldb + c8;
    short* dA0 = &As[r][c8];
    short* dA1 = &As[r + 64][c8];
    short* dB0 = &Bs[r][c8];
    short* dB1 = &Bs[r + 64][c8];

    // prefetch K-tile 0 into registers (scalars)
    float4 a0lo, a0hi, a1lo, a1hi;   // AF32 path
    uint4 a0p, a1p;                  // bf16 path
    uint4 b0p, b1p;
    if (AF32) {
        a0lo = *(const float4*)fA0; a0hi = *(const float4*)(fA0 + 4);
        a1lo = *(const float4*)fA1; a1hi = *(const float4*)(fA1 + 4);
    } else {
        a0p = *(const uint4*)sA0;
        a1p = *(const uint4*)sA1;
    }
    b0p = *(const uint4*)sB0;
    b1p = *(const uint4*)sB1;

    for (int k0 = 0; k0 < K; k0 += 64) {
        __syncthreads();                    // prev compute done; LDS writable
        if (AF32) {
            *(uint4*)dA0 = pack8(a0lo, a0hi);
            *(uint4*)dA1 = pack8(a1lo, a1hi);
        } else {
            *(uint4*)dA0 = a0p;
            *(uint4*)dA1 = a1p;
        }
        *(uint4*)dB0 = b0p;
        *(uint4*)dB1 = b1p;
        if (k0 + 64 < K) {                  // T14: issue next tile now
            if (AF32) {
                a0lo = *(const float4*)(fA0 + k0 + 64);
                a0hi = *(const float4*)(fA0 + k0 + 68);
                a1lo = *(const float4*)(fA1 + k0 + 64);
                a1hi = *(const float4*)(fA1 + k0 + 68);
            } else {
                a0p = *(const uint4*)(sA0 + k0 + 64);
                a1p = *(const uint4*)(sA1 + k0 + 64);
            }
            b0p = *(const uint4*)(sB0 + k0 + 64);
            b1p = *(const uint4*)(sB1 + k0 + 64);
        }
        __syncthreads();                    // LDS tile ready
#pragma unroll
        for (int kc = 0; kc < 2; ++kc) {
            bf16x8 a0 = *(const bf16x8*)&As[wm * 32 + ln][kc * 32 + quad * 8];
            bf16x8 a1 = *(const bf16x8*)&As[wm * 32 + 16 + ln][kc * 32 + quad * 8];
#pragma unroll
            for (int ni = 0; ni < 4; ++ni) {
                bf16x8 b = *(const bf16x8*)&Bs[wn * 64 + ni * 16 + ln][kc * 32 + quad * 8];
                acc[0][ni] = __builtin_amdgcn_mfma_f32_16x16x32_bf16(a0, b, acc[0][ni], 0, 0, 0);
                acc[1][ni] = __builtin_amdgcn_mfma_f32_16x16x32_bf16(a1, b, acc[1][ni], 0, 0, 0);
            }
        }
    }
}

// ---------------------------------------------------------------------------
// Stage 1: one block = (m-tile, head h); A = fp32 x directly (fused convert).
// Head index is FASTEST within an XCD so the 12 readers of each x-panel are
// dispatch-adjacent (panel served from L2 once; fp32 doubles panel size).
// (512,2): reg cap 128 (R9 lesson: 2nd arg acts as min-blocks/CU here).
// ---------------------------------------------------------------------------
__global__ __launch_bounds__(512, 2) void proj_kv_mfma(
    const float* __restrict__ x,
    const short* __restrict__ kTw,   // [h][p][e] bf16
    const short* __restrict__ vTw,
    short* __restrict__ kb,          // [b][h][s][p]
    short* __restrict__ vTb)         // [b][h][p][s]
{
    __shared__ short As[128][72];
    __shared__ short Bs[128][72];
    const int tid = threadIdx.x;
    const int w = tid >> 6, lane = tid & 63, quad = lane >> 4, ln = lane & 15;
    const int wm = w & 3, wn = w >> 2;

    const int lid = (int)blockIdx.x;          // 768 blocks
    const int xcd = lid & 7, s = lid >> 3;    // s in [0,96)
    const int h = s % 12, mloc = s / 12;      // h fastest
    const int m0 = (xcd * 8 + mloc) * 128;

    f32x4 acc[2][4] = {};
    mfma_gemm_128x128<true>(x + (size_t)m0 * E_, E_,
                            kTw + (size_t)h * P_ * E_, vTw + (size_t)h * P_ * E_, E_, E_,
                            As, Bs, acc);

    const int b = m0 >> 10;
    const int sbase = (m0 & 1023) + wm * 32;
    if (wn == 0) {
        short* outp = kb + ((size_t)(b * H_ + h)) * S_ * P_;
#pragma unroll
        for (int mi = 0; mi < 2; ++mi)
#pragma unroll
            for (int ni = 0; ni < 4; ++ni)
#pragma unroll
                for (int r = 0; r < 4; ++r) {
                    int ss = sbase + mi * 16 + quad * 4 + r;
                    outp[(size_t)ss * P_ + ni * 16 + ln] = f2bf(acc[mi][ni][r]);
                }
    } else {
        short* outp = vTb + ((size_t)(b * H_ + h)) * P_ * S_;
#pragma unroll
        for (int mi = 0; mi < 2; ++mi)
#pragma unroll
            for (int ni = 0; ni < 4; ++ni) {
                int p = ni * 16 + ln;
                int ss = sbase + mi * 16 + quad * 4;  // 4 consecutive s in regs
                ushort4 u;
                u.x = (unsigned short)f2bf(acc[mi][ni][0]);
                u.y = (unsigned short)f2bf(acc[mi][ni][1]);
                u.z = (unsigned short)f2bf(acc[mi][ni][2]);
                u.w = (unsigned short)f2bf(acc[mi][ni][3]);
                *(ushort4*)(outp + (size_t)p * S_ + ss) = u;
            }
    }
}

// ---------------------------------------------------------------------------
// Stage 2: qv[b,h] = q_heads[h] @ v[b,h]; A = fp32 q_heads directly (fused
// convert). N=128 via batch pairs; bp fastest -> the 4 readers of each
// A-panel are co-resident.
// ---------------------------------------------------------------------------
__global__ __launch_bounds__(512, 2) void qv_mfma(
    const float* __restrict__ qheads,
    const short* __restrict__ vTb,
    short* __restrict__ qvb)
{
    __shared__ short As[128][72];
    __shared__ short Bs[128][72];
    const int tid = threadIdx.x;
    const int w = tid >> 6, lane = tid & 63, quad = lane >> 4, ln = lane & 15;
    const int wm = w & 3, wn = w >> 2;

    const int lid = (int)blockIdx.x;             // 384 blocks
    const int xcd = lid & 7, s = lid >> 3;       // s in [0,48)
    const int virt = xcd * 48 + s;               // h-major, XCD-chunked
    const int h = virt >> 5;                     // 12 heads x 32 blocks
    const int rem = virt & 31;
    const int mt = rem >> 2, bp = rem & 3;       // 8 m-tiles, 4 b-pairs
    const int m0 = mt * 128;

    const short* Bv0 = vTb + (size_t)((bp * 2 + 0) * H_ + h) * P_ * S_;
    const short* Bv1 = vTb + (size_t)((bp * 2 + 1) * H_ + h) * P_ * S_;

    f32x4 acc[2][4] = {};
    mfma_gemm_128x128<true>(qheads + (size_t)h * S_ * S_ + (size_t)m0 * S_, S_,
                            Bv0, Bv1, S_, S_, As, Bs, acc);

    const int b = bp * 2 + wn;
    short* outp = qvb + (size_t)(b * H_ + h) * S_ * P_;
#pragma unroll
    for (int mi = 0; mi < 2; ++mi)
#pragma unroll
        for (int ni = 0; ni < 4; ++ni)
#pragma unroll
            for (int r = 0; r < 4; ++r) {
                int ss = m0 + wm * 32 + mi * 16 + quad * 4 + r;
                outp[(size_t)ss * P_ + ni * 16 + ln] = f2bf(acc[mi][ni][r]);
            }
}

// ---------------------------------------------------------------------------
// Stage 3: flash attention, REVERTED to R9 (best measured): block-shared K/V
// staging, q-block pair balance, per-wave-owned outputs. R10's key-split was
// neutral-to-negative (+3us, 3.5x bank conflicts from shared-P writes).
// (512,4) proven: VGPR ~60, zero spill.
// ---------------------------------------------------------------------------
__global__ __launch_bounds__(512, 4) void flash_mfma(
    const short* __restrict__ kb,
    const short* __restrict__ qvb,
    const short* __restrict__ vTb,
    short* __restrict__ attn2)
{
    __shared__ short Ks[64][72];
    __shared__ short Vts[64][72];
    __shared__ short Ps[8][16][72];

    const int tid = threadIdx.x;
    const int w = tid >> 6, lane = tid & 63, quad = lane >> 4, ln = lane & 15;
    const int wq = w & 3;                 // 16-row strip within q-block
    const int wsel = w >> 2;              // 0 = hi q-block, 1 = lo

    const int lid = (int)blockIdx.x;      // 768 blocks, XCD-local bh
    const int xcd = lid & 7, sl = lid >> 3;
    const int bh  = xcd * 12 + (sl >> 3);
    const int pair = sl & 7;
    const int qhi = 15 - pair;
    const int qb  = wsel ? pair : qhi;
    const int b = bh / H_, h = bh % H_;

    const short* Q  = kb  + (size_t)bh * S_ * P_ + ((size_t)qb * 64 + wq * 16) * P_;
    const short* K  = qvb + (size_t)bh * S_ * P_;
    const short* Vt = vTb + (size_t)bh * P_ * S_;

    // Q fragments direct from global (one-time)
    bf16x8 qf[2];
    qf[0] = *(const bf16x8*)(Q + (size_t)ln * P_ + quad * 8);
    qf[1] = *(const bf16x8*)(Q + (size_t)ln * P_ + 32 + quad * 8);

    // staging: thread -> (row, 16B chunk); K rows stride P_, Vt rows stride S_
    const int krow = tid >> 3, kc8 = (tid & 7) * 8;
    const short* Kst = K + (size_t)krow * P_ + kc8;      // + jt*64*P_
    const short* Vst = Vt + (size_t)krow * S_ + kc8;     // + jt*64
    uint4 rK = *(const uint4*)Kst;                       // tile 0 prefetch
    uint4 rV = *(const uint4*)Vst;

    f32x4 o[4] = {};
    float l[4] = {};
    short (*Pw)[72] = Ps[w];
    const float c2 = 0.03608439182435161f * 1.4426950408889634f; // scale*log2e
    const int rowbase = wq * 16;

    for (int jt = 0; jt <= qhi; ++jt) {
        __syncthreads();                   // prev compute done; LDS writable
        *(uint4*)&Ks[krow][kc8] = rK;
        *(uint4*)&Vts[krow][kc8] = rV;
        if (jt < qhi) {                    // T14: issue next tile now
            rK = *(const uint4*)(Kst + (size_t)(jt + 1) * 64 * P_);
            rV = *(const uint4*)(Vst + (jt + 1) * 64);
        }
        __syncthreads();                   // LDS tile ready

        if (jt <= qb) {
            const bool diag = (jt == qb);
            f32x4 s[4] = {};
#pragma unroll
            for (int kc = 0; kc < 2; ++kc)
#pragma unroll
                for (int ni = 0; ni < 4; ++ni) {
                    bf16x8 kf = *(const bf16x8*)&Ks[ni * 16 + ln][kc * 32 + quad * 8];
                    s[ni] = __builtin_amdgcn_mfma_f32_16x16x32_bf16(qf[kc], kf, s[ni], 0, 0, 0);
                }

#pragma unroll
            for (int r = 0; r < 4; ++r) {
                const int row = quad * 4 + r;
                float p[4];
#pragma unroll
                for (int ni = 0; ni < 4; ++ni) {
                    float v = __builtin_amdgcn_exp2f(c2 * s[ni][r]);
                    if (diag && (ni * 16 + ln) > (rowbase + row)) v = 0.f;
                    p[ni] = v;
                    l[r] += v;
                }
#pragma unroll
                for (int ni = 0; ni < 4; ++ni)
                    Pw[row][ni * 16 + ln] = f2bf_hw(p[ni]);
            }

#pragma unroll
            for (int kc = 0; kc < 2; ++kc) {
                bf16x8 pa = *(const bf16x8*)&Pw[ln][kc * 32 + quad * 8];
#pragma unroll
                for (int ni = 0; ni < 4; ++ni) {
                    bf16x8 vb = *(const bf16x8*)&Vts[ni * 16 + ln][kc * 32 + quad * 8];
                    o[ni] = __builtin_amdgcn_mfma_f32_16x16x32_bf16(pa, vb, o[ni], 0, 0, 0);
                }
            }
        }
    }

    // epilogue: per-wave row-sum reduce + store (wave fully owns its rows)
#pragma unroll
    for (int r = 0; r < 4; ++r) {
        float lv = l[r];
#pragma unroll
        for (int off = 1; off < 16; off <<= 1)
            lv += __shfl_xor(lv, off, 16);
        float inv = 1.0f / lv;
        int gi = qb * 64 + rowbase + quad * 4 + r;
#pragma unroll
        for (int ni = 0; ni < 4; ++ni)
            attn2[((size_t)b * S_ + gi) * (H_ * P_) + h * P_ + ni * 16 + ln] =
                f2bf(o[ni][r] * inv);
    }
}

// ---------------------------------------------------------------------------
// Stage 4: out = attn2 @ lifting; N=128 via column pairs. A stays bf16.
// ---------------------------------------------------------------------------
__global__ __launch_bounds__(512, 2) void lift_mfma(
    const short* __restrict__ attn2,
    const short* __restrict__ liftT,
    float* __restrict__ outp)
{
    __shared__ short As[128][72];
    __shared__ short Bs[128][72];
    const int tid = threadIdx.x;
    const int w = tid >> 6, lane = tid & 63, quad = lane >> 4, ln = lane & 15;
    const int wm = w & 3, wn = w >> 2;

    const int lid = (int)blockIdx.x;             // 384 blocks
    const int xcd = lid & 7, s = lid >> 3;       // s in [0,48)
    const int mloc = s & 7, np = s >> 3;         // 8 m-tiles/xcd, 6 n-pairs
    const int m0 = (xcd * 8 + mloc) * 128;
    const int n0 = np * 128;

    f32x4 acc[2][4] = {};
    mfma_gemm_128x128<false>(attn2 + (size_t)m0 * E_, E_,
                             liftT + (size_t)n0 * E_, liftT + (size_t)(n0 + 64) * E_, E_, E_,
                             As, Bs, acc);

#pragma unroll
    for (int mi = 0; mi < 2; ++mi)
#pragma unroll
        for (int ni = 0; ni < 4; ++ni)
#pragma unroll
            for (int r = 0; r < 4; ++r) {
                int m = m0 + wm * 32 + mi * 16 + quad * 4 + r;
                outp[(size_t)m * E_ + n0 + wn * 64 + ni * 16 + ln] = acc[mi][ni][r];
            }
}

extern "C" void kernel_launch(void* const* d_in, const int* in_sizes, int n_in,
                              void* d_out, int out_size, void* d_ws, size_t ws_size,
                              hipStream_t stream) {
    (void)in_sizes; (void)n_in; (void)out_size; (void)ws_size;
    const float* x       = (const float*)d_in[0];
    const float* kproj   = (const float*)d_in[1];
    const float* vproj   = (const float*)d_in[2];
    const float* qheads  = (const float*)d_in[3];
    const float* lifting = (const float*)d_in[4];
    float* out = (float*)d_out;

    short* ws = (short*)d_ws;
    const size_t N_W   = (size_t)H_ * P_ * E_;          //    589,824
    const size_t N_L   = (size_t)E_ * E_;               //    589,824
    const size_t N_KV  = (size_t)B_ * H_ * S_ * P_;     // 6,291,456

    short* kTw   = ws;                 ws += N_W;
    short* vTw   = ws;                 ws += N_W;
    short* liftT = ws;                 ws += N_L;
    short* kb    = ws;                 ws += N_KV;
    short* vTb   = ws;                 ws += N_KV;
    short* qvb   = ws;                 ws += N_KV;
    short* attn2 = ws;                 ws += N_KV;

    conv_fused<<<dim3(432), 256, 0, stream>>>(kproj, vproj, lifting, kTw, vTw, liftT);
    proj_kv_mfma<<<dim3(768), 512, 0, stream>>>(x, kTw, vTw, kb, vTb);
    qv_mfma<<<dim3(384), 512, 0, stream>>>(qheads, vTb, qvb);
    flash_mfma<<<dim3(768), 512, 0, stream>>>(kb, qvb, vTb, attn2);
    lift_mfma<<<dim3(384), 512, 0, stream>>>(attn2, liftT, out);
}

// Round 12
// 218.531 us; speedup vs baseline: 1.0694x; 1.0694x over previous
//
#include <hip/hip_runtime.h>
#include <hip/hip_bf16.h>
#include <math.h>

#define B_ 8
#define S_ 1024
#define E_ 768
#define H_ 12
#define P_ 64

typedef __attribute__((ext_vector_type(8))) short bf16x8;
typedef __attribute__((ext_vector_type(4))) float f32x4;

__device__ __forceinline__ short f2bf(float f) {
    union { float f; unsigned u; } v; v.f = f;
    unsigned r = v.u + 0x7FFFu + ((v.u >> 16) & 1u);  // round-to-nearest-even
    return (short)(r >> 16);
}

// HW bf16 convert (compiler emits v_cvt path; m240: beats hand asm).
__device__ __forceinline__ short f2bf_hw(float f) {
    union { __hip_bfloat16 h; short s; } cv;
    cv.h = __float2bfloat16(f);
    return cv.s;
}

// ---------------------------------------------------------------------------
// Fused preprocessing (R9 structure + G11 grid-stride for the streaming part).
// Blocks [0,2048): grid-stride fp32->bf16 convert of x (1,572,864 float4s)
// then q_heads (3,145,728 float4s). Blocks [2048,2480): weight transposes.
// ---------------------------------------------------------------------------
#define CONV_STREAM_BLOCKS 2048
#define N_X4  1572864
#define N_ALL4 4718592

__device__ __forceinline__ void conv_T_body(
    const float* __restrict__ src0, short* __restrict__ dst0, int R, int C,
    int bx, int by, int bz, short (*T)[72])
{
    const int t = threadIdx.x;
    const int r0 = bx * 64, c0 = by * 64;
    const size_t bo = (size_t)bz * R * C;
    const float* src = src0 + bo;
    short* dst = dst0 + bo;
#pragma unroll
    for (int i = 0; i < 4; ++i) {
        int id = i * 256 + t;
        int r = id >> 4, c4 = id & 15;
        float4 f = *(const float4*)(src + (size_t)(r0 + r) * C + c0 + c4 * 4);
        T[c4 * 4 + 0][r] = f2bf(f.x);
        T[c4 * 4 + 1][r] = f2bf(f.y);
        T[c4 * 4 + 2][r] = f2bf(f.z);
        T[c4 * 4 + 3][r] = f2bf(f.w);
    }
    __syncthreads();
#pragma unroll
    for (int i = 0; i < 2; ++i) {
        int id = i * 256 + t;
        int cc = id >> 3, r8 = id & 7;
        *(uint4*)(dst + (size_t)(c0 + cc) * R + r0 + r8 * 8) = *(const uint4*)&T[cc][r8 * 8];
    }
}

__global__ __launch_bounds__(256) void conv_fused(
    const float* __restrict__ x, const float* __restrict__ qh,
    const float* __restrict__ kproj, const float* __restrict__ vproj,
    const float* __restrict__ lifting,
    short* __restrict__ xb, short* __restrict__ qhb,
    short* __restrict__ kTw, short* __restrict__ vTw, short* __restrict__ liftT)
{
    __shared__ short T[64][72];
    const int bid = (int)blockIdx.x;
    if (bid < CONV_STREAM_BLOCKS) {
        // grid-stride streaming convert (x then q_heads)
        for (int i = bid * 256 + (int)threadIdx.x; i < N_ALL4;
             i += CONV_STREAM_BLOCKS * 256) {
            const float4* src; ushort4* dst; int idx;
            if (i < N_X4) { src = (const float4*)x;  dst = (ushort4*)xb;  idx = i; }
            else          { src = (const float4*)qh; dst = (ushort4*)qhb; idx = i - N_X4; }
            float4 f = src[idx];
            ushort4 u;
            u.x = (unsigned short)f2bf(f.x);
            u.y = (unsigned short)f2bf(f.y);
            u.z = (unsigned short)f2bf(f.z);
            u.w = (unsigned short)f2bf(f.w);
            dst[idx] = u;
        }
    } else if (bid < CONV_STREAM_BLOCKS + 144) {
        int r = bid - CONV_STREAM_BLOCKS;          // kproj: (12 tiles, 12 heads)
        conv_T_body(kproj, kTw, E_, P_, r % 12, 0, r / 12, T);
    } else if (bid < CONV_STREAM_BLOCKS + 288) {
        int r = bid - (CONV_STREAM_BLOCKS + 144);  // vproj
        conv_T_body(vproj, vTw, E_, P_, r % 12, 0, r / 12, T);
    } else {
        int r = bid - (CONV_STREAM_BLOCKS + 288);  // lifting: (12,12)
        conv_T_body(lifting, liftT, E_, E_, r % 12, r / 12, 0, T);
    }
}

// ---------------------------------------------------------------------------
// 8-wave MFMA GEMM core: C(128x128) = A(128xK) @ [B0;B1](128xK)^T.
// T14 register-prefetch double-buffer, SCALARIZED staging state. (R9 proven)
// ---------------------------------------------------------------------------
__device__ __forceinline__ void mfma_gemm_128x128(
    const short* __restrict__ A, int lda,
    const short* __restrict__ B0, const short* __restrict__ B1, int ldb, int K,
    short (*As)[72], short (*Bs)[72], f32x4 (&acc)[2][4])
{
    const int tid = threadIdx.x;
    const int w = tid >> 6, lane = tid & 63, quad = lane >> 4, ln = lane & 15;
    const int wm = w & 3, wn = w >> 2;

    const int r = tid >> 3, c8 = (tid & 7) * 8;
    const short* sA0 = A  + (size_t)r * lda + c8;
    const short* sA1 = A  + (size_t)(r + 64) * lda + c8;
    const short* sB0 = B0 + (size_t)r * ldb + c8;
    const short* sB1 = B1 + (size_t)r * ldb + c8;
    short* dA0 = &As[r][c8];
    short* dA1 = &As[r + 64][c8];
    short* dB0 = &Bs[r][c8];
    short* dB1 = &Bs[r + 64][c8];

    // prefetch K-tile 0 into registers (scalars)
    uint4 a0p = *(const uint4*)sA0;
    uint4 a1p = *(const uint4*)sA1;
    uint4 b0p = *(const uint4*)sB0;
    uint4 b1p = *(const uint4*)sB1;

    for (int k0 = 0; k0 < K; k0 += 64) {
        __syncthreads();                    // prev compute done; LDS writable
        *(uint4*)dA0 = a0p;
        *(uint4*)dA1 = a1p;
        *(uint4*)dB0 = b0p;
        *(uint4*)dB1 = b1p;
        if (k0 + 64 < K) {                  // T14: issue next tile now
            a0p = *(const uint4*)(sA0 + k0 + 64);
            a1p = *(const uint4*)(sA1 + k0 + 64);
            b0p = *(const uint4*)(sB0 + k0 + 64);
            b1p = *(const uint4*)(sB1 + k0 + 64);
        }
        __syncthreads();                    // LDS tile ready
#pragma unroll
        for (int kc = 0; kc < 2; ++kc) {
            bf16x8 a0 = *(const bf16x8*)&As[wm * 32 + ln][kc * 32 + quad * 8];
            bf16x8 a1 = *(const bf16x8*)&As[wm * 32 + 16 + ln][kc * 32 + quad * 8];
#pragma unroll
            for (int ni = 0; ni < 4; ++ni) {
                bf16x8 b = *(const bf16x8*)&Bs[wn * 64 + ni * 16 + ln][kc * 32 + quad * 8];
                acc[0][ni] = __builtin_amdgcn_mfma_f32_16x16x32_bf16(a0, b, acc[0][ni], 0, 0, 0);
                acc[1][ni] = __builtin_amdgcn_mfma_f32_16x16x32_bf16(a1, b, acc[1][ni], 0, 0, 0);
            }
        }
    }
}

// ---------------------------------------------------------------------------
// Stage 1: one block = (m-tile, head h); computes BOTH k (wn=0) and v (wn=1).
// (512,2): reg cap 128 (R9 lesson: 2nd arg acts as min-blocks/CU here;
// (512,6)->~42 regs spill, (512,4)->64, prefetch core needs ~75+).
// A stays bf16: R11 lesson — fusing the fp32 convert into staging multiplies
// fp32 traffic by the reuse factor (12x) and regressed proj 35->48 us.
// ---------------------------------------------------------------------------
__global__ __launch_bounds__(512, 2) void proj_kv_mfma(
    const short* __restrict__ xb,
    const short* __restrict__ kTw,   // [h][p][e] bf16
    const short* __restrict__ vTw,
    short* __restrict__ kb,          // [b][h][s][p]
    short* __restrict__ vTb)         // [b][h][p][s]
{
    __shared__ short As[128][72];
    __shared__ short Bs[128][72];
    const int tid = threadIdx.x;
    const int w = tid >> 6, lane = tid & 63, quad = lane >> 4, ln = lane & 15;
    const int wm = w & 3, wn = w >> 2;

    const int lid = (int)blockIdx.x;          // 768 blocks
    const int xcd = lid & 7, s = lid >> 3;    // s in [0,96)
    const int mloc = s & 7, h = s >> 3;       // 8 m-tiles/xcd, 12 heads
    const int m0 = (xcd * 8 + mloc) * 128;

    f32x4 acc[2][4] = {};
    mfma_gemm_128x128(xb + (size_t)m0 * E_, E_,
                      kTw + (size_t)h * P_ * E_, vTw + (size_t)h * P_ * E_, E_, E_,
                      As, Bs, acc);

    const int b = m0 >> 10;
    const int sbase = (m0 & 1023) + wm * 32;
    if (wn == 0) {
        short* outp = kb + ((size_t)(b * H_ + h)) * S_ * P_;
#pragma unroll
        for (int mi = 0; mi < 2; ++mi)
#pragma unroll
            for (int ni = 0; ni < 4; ++ni)
#pragma unroll
                for (int r = 0; r < 4; ++r) {
                    int ss = sbase + mi * 16 + quad * 4 + r;
                    outp[(size_t)ss * P_ + ni * 16 + ln] = f2bf(acc[mi][ni][r]);
                }
    } else {
        short* outp = vTb + ((size_t)(b * H_ + h)) * P_ * S_;
#pragma unroll
        for (int mi = 0; mi < 2; ++mi)
#pragma unroll
            for (int ni = 0; ni < 4; ++ni) {
                int p = ni * 16 + ln;
                int ss = sbase + mi * 16 + quad * 4;  // 4 consecutive s in regs
                ushort4 u;
                u.x = (unsigned short)f2bf(acc[mi][ni][0]);
                u.y = (unsigned short)f2bf(acc[mi][ni][1]);
                u.z = (unsigned short)f2bf(acc[mi][ni][2]);
                u.w = (unsigned short)f2bf(acc[mi][ni][3]);
                *(ushort4*)(outp + (size_t)p * S_ + ss) = u;
            }
    }
}

// ---------------------------------------------------------------------------
// Stage 2: qv[b,h] = q_heads[h] @ v[b,h]; N=128 via batch pairs.
// ---------------------------------------------------------------------------
__global__ __launch_bounds__(512, 2) void qv_mfma(
    const short* __restrict__ qhb,
    const short* __restrict__ vTb,
    short* __restrict__ qvb)
{
    __shared__ short As[128][72];
    __shared__ short Bs[128][72];
    const int tid = threadIdx.x;
    const int w = tid >> 6, lane = tid & 63, quad = lane >> 4, ln = lane & 15;
    const int wm = w & 3, wn = w >> 2;

    const int lid = (int)blockIdx.x;             // 384 blocks
    const int xcd = lid & 7, s = lid >> 3;       // s in [0,48)
    const int virt = xcd * 48 + s;               // h-major, XCD-chunked
    const int h = virt >> 5;                     // 12 heads x 32 blocks
    const int rem = virt & 31;
    const int mt = rem >> 2, bp = rem & 3;       // 8 m-tiles, 4 b-pairs
    const int m0 = mt * 128;

    const short* Bv0 = vTb + (size_t)((bp * 2 + 0) * H_ + h) * P_ * S_;
    const short* Bv1 = vTb + (size_t)((bp * 2 + 1) * H_ + h) * P_ * S_;

    f32x4 acc[2][4] = {};
    mfma_gemm_128x128(qhb + (size_t)h * S_ * S_ + (size_t)m0 * S_, S_,
                      Bv0, Bv1, S_, S_, As, Bs, acc);

    const int b = bp * 2 + wn;
    short* outp = qvb + (size_t)(b * H_ + h) * S_ * P_;
#pragma unroll
    for (int mi = 0; mi < 2; ++mi)
#pragma unroll
        for (int ni = 0; ni < 4; ++ni)
#pragma unroll
            for (int r = 0; r < 4; ++r) {
                int ss = m0 + wm * 32 + mi * 16 + quad * 4 + r;
                outp[(size_t)ss * P_ + ni * 16 + ln] = f2bf(acc[mi][ni][r]);
            }
}

// ---------------------------------------------------------------------------
// Stage 3: flash attention (R9 exact: block-shared K/V staging, q-block pair
// balance, per-wave-owned outputs; R10's key-split reverted — +3us and 3.5x
// bank conflicts). (512,4) proven: VGPR ~60, zero spill.
// ---------------------------------------------------------------------------
__global__ __launch_bounds__(512, 4) void flash_mfma(
    const short* __restrict__ kb,
    const short* __restrict__ qvb,
    const short* __restrict__ vTb,
    short* __restrict__ attn2)
{
    __shared__ short Ks[64][72];
    __shared__ short Vts[64][72];
    __shared__ short Ps[8][16][72];

    const int tid = threadIdx.x;
    const int w = tid >> 6, lane = tid & 63, quad = lane >> 4, ln = lane & 15;
    const int wq = w & 3;                 // 16-row strip within q-block
    const int wsel = w >> 2;              // 0 = hi q-block, 1 = lo

    const int lid = (int)blockIdx.x;      // 768 blocks, XCD-local bh
    const int xcd = lid & 7, sl = lid >> 3;
    const int bh  = xcd * 12 + (sl >> 3);
    const int pair = sl & 7;
    const int qhi = 15 - pair;
    const int qb  = wsel ? pair : qhi;
    const int b = bh / H_, h = bh % H_;

    const short* Q  = kb  + (size_t)bh * S_ * P_ + ((size_t)qb * 64 + wq * 16) * P_;
    const short* K  = qvb + (size_t)bh * S_ * P_;
    const short* Vt = vTb + (size_t)bh * P_ * S_;

    // Q fragments direct from global (one-time)
    bf16x8 qf[2];
    qf[0] = *(const bf16x8*)(Q + (size_t)ln * P_ + quad * 8);
    qf[1] = *(const bf16x8*)(Q + (size_t)ln * P_ + 32 + quad * 8);

    // staging: thread -> (row, 16B chunk); K rows stride P_, Vt rows stride S_
    const int krow = tid >> 3, kc8 = (tid & 7) * 8;
    const short* Kst = K + (size_t)krow * P_ + kc8;      // + jt*64*P_
    const short* Vst = Vt + (size_t)krow * S_ + kc8;     // + jt*64
    uint4 rK = *(const uint4*)Kst;                       // tile 0 prefetch
    uint4 rV = *(const uint4*)Vst;

    f32x4 o[4] = {};
    float l[4] = {};
    short (*Pw)[72] = Ps[w];
    const float c2 = 0.03608439182435161f * 1.4426950408889634f; // scale*log2e
    const int rowbase = wq * 16;

    for (int jt = 0; jt <= qhi; ++jt) {
        __syncthreads();                   // prev compute done; LDS writable
        *(uint4*)&Ks[krow][kc8] = rK;
        *(uint4*)&Vts[krow][kc8] = rV;
        if (jt < qhi) {                    // T14: issue next tile now
            rK = *(const uint4*)(Kst + (size_t)(jt + 1) * 64 * P_);
            rV = *(const uint4*)(Vst + (jt + 1) * 64);
        }
        __syncthreads();                   // LDS tile ready

        if (jt <= qb) {
            const bool diag = (jt == qb);
            f32x4 s[4] = {};
#pragma unroll
            for (int kc = 0; kc < 2; ++kc)
#pragma unroll
                for (int ni = 0; ni < 4; ++ni) {
                    bf16x8 kf = *(const bf16x8*)&Ks[ni * 16 + ln][kc * 32 + quad * 8];
                    s[ni] = __builtin_amdgcn_mfma_f32_16x16x32_bf16(qf[kc], kf, s[ni], 0, 0, 0);
                }

#pragma unroll
            for (int r = 0; r < 4; ++r) {
                const int row = quad * 4 + r;
                float p[4];
#pragma unroll
                for (int ni = 0; ni < 4; ++ni) {
                    float v = __builtin_amdgcn_exp2f(c2 * s[ni][r]);
                    if (diag && (ni * 16 + ln) > (rowbase + row)) v = 0.f;
                    p[ni] = v;
                    l[r] += v;
                }
#pragma unroll
                for (int ni = 0; ni < 4; ++ni)
                    Pw[row][ni * 16 + ln] = f2bf_hw(p[ni]);
            }

#pragma unroll
            for (int kc = 0; kc < 2; ++kc) {
                bf16x8 pa = *(const bf16x8*)&Pw[ln][kc * 32 + quad * 8];
#pragma unroll
                for (int ni = 0; ni < 4; ++ni) {
                    bf16x8 vb = *(const bf16x8*)&Vts[ni * 16 + ln][kc * 32 + quad * 8];
                    o[ni] = __builtin_amdgcn_mfma_f32_16x16x32_bf16(pa, vb, o[ni], 0, 0, 0);
                }
            }
        }
    }

    // epilogue: per-wave row-sum reduce + store (wave fully owns its rows)
#pragma unroll
    for (int r = 0; r < 4; ++r) {
        float lv = l[r];
#pragma unroll
        for (int off = 1; off < 16; off <<= 1)
            lv += __shfl_xor(lv, off, 16);
        float inv = 1.0f / lv;
        int gi = qb * 64 + rowbase + quad * 4 + r;
#pragma unroll
        for (int ni = 0; ni < 4; ++ni)
            attn2[((size_t)b * S_ + gi) * (H_ * P_) + h * P_ + ni * 16 + ln] =
                f2bf(o[ni][r] * inv);
    }
}

// ---------------------------------------------------------------------------
// Stage 4: out = attn2 @ lifting; N=128 via column pairs.
// ---------------------------------------------------------------------------
__global__ __launch_bounds__(512, 2) void lift_mfma(
    const short* __restrict__ attn2,
    const short* __restrict__ liftT,
    float* __restrict__ outp)
{
    __shared__ short As[128][72];
    __shared__ short Bs[128][72];
    const int tid = threadIdx.x;
    const int w = tid >> 6, lane = tid & 63, quad = lane >> 4, ln = lane & 15;
    const int wm = w & 3, wn = w >> 2;

    const int lid = (int)blockIdx.x;             // 384 blocks
    const int xcd = lid & 7, s = lid >> 3;       // s in [0,48)
    const int mloc = s & 7, np = s >> 3;         // 8 m-tiles/xcd, 6 n-pairs
    const int m0 = (xcd * 8 + mloc) * 128;
    const int n0 = np * 128;

    f32x4 acc[2][4] = {};
    mfma_gemm_128x128(attn2 + (size_t)m0 * E_, E_,
                      liftT + (size_t)n0 * E_, liftT + (size_t)(n0 + 64) * E_, E_, E_,
                      As, Bs, acc);

#pragma unroll
    for (int mi = 0; mi < 2; ++mi)
#pragma unroll
        for (int ni = 0; ni < 4; ++ni)
#pragma unroll
            for (int r = 0; r < 4; ++r) {
                int m = m0 + wm * 32 + mi * 16 + quad * 4 + r;
                outp[(size_t)m * E_ + n0 + wn * 64 + ni * 16 + ln] = acc[mi][ni][r];
            }
}

extern "C" void kernel_launch(void* const* d_in, const int* in_sizes, int n_in,
                              void* d_out, int out_size, void* d_ws, size_t ws_size,
                              hipStream_t stream) {
    (void)in_sizes; (void)n_in; (void)out_size; (void)ws_size;
    const float* x       = (const float*)d_in[0];
    const float* kproj   = (const float*)d_in[1];
    const float* vproj   = (const float*)d_in[2];
    const float* qheads  = (const float*)d_in[3];
    const float* lifting = (const float*)d_in[4];
    float* out = (float*)d_out;

    short* ws = (short*)d_ws;
    const size_t N_X   = (size_t)B_ * S_ * E_;          // 6,291,456
    const size_t N_QH  = (size_t)H_ * S_ * S_;          // 12,582,912
    const size_t N_W   = (size_t)H_ * P_ * E_;          //    589,824
    const size_t N_L   = (size_t)E_ * E_;               //    589,824
    const size_t N_KV  = (size_t)B_ * H_ * S_ * P_;     // 6,291,456

    short* xb    = ws;                 ws += N_X;
    short* qhb   = ws;                 ws += N_QH;
    short* kTw   = ws;                 ws += N_W;
    short* vTw   = ws;                 ws += N_W;
    short* liftT = ws;                 ws += N_L;
    short* kb    = ws;                 ws += N_KV;
    short* vTb   = ws;                 ws += N_KV;
    short* qvb   = ws;                 ws += N_KV;
    short* attn2 = ws;                 ws += N_KV;

    conv_fused<<<dim3(CONV_STREAM_BLOCKS + 432), 256, 0, stream>>>(
        x, qheads, kproj, vproj, lifting, xb, qhb, kTw, vTw, liftT);
    proj_kv_mfma<<<dim3(768), 512, 0, stream>>>(xb, kTw, vTw, kb, vTb);
    qv_mfma<<<dim3(384), 512, 0, stream>>>(qhb, vTb, qvb);
    flash_mfma<<<dim3(768), 512, 0, stream>>>(kb, qvb, vTb, attn2);
    lift_mfma<<<dim3(384), 512, 0, stream>>>(attn2, liftT, out);
}

// Round 14
// 216.965 us; speedup vs baseline: 1.0771x; 1.0072x over previous
//
#include <hip/hip_runtime.h>
#include <hip/hip_bf16.h>
#include <math.h>

#define B_ 8
#define S_ 1024
#define E_ 768
#define H_ 12
#define P_ 64

typedef __attribute__((ext_vector_type(8))) short bf16x8;
typedef __attribute__((ext_vector_type(4))) float f32x4;

__device__ __forceinline__ short f2bf(float f) {
    union { float f; unsigned u; } v; v.f = f;
    unsigned r = v.u + 0x7FFFu + ((v.u >> 16) & 1u);  // round-to-nearest-even
    return (short)(r >> 16);
}

// HW bf16 convert (compiler emits v_cvt path; m240: beats hand asm).
__device__ __forceinline__ short f2bf_hw(float f) {
    union { __hip_bfloat16 h; short s; } cv;
    cv.h = __float2bfloat16(f);
    return cv.s;
}

// ---------------------------------------------------------------------------
// Fused preprocessing (grid-stride streaming converts + weight transposes).
// Blocks [0,2048): x then q_heads fp32->bf16. [2048,2480): transposes.
// ---------------------------------------------------------------------------
#define CONV_STREAM_BLOCKS 2048
#define N_X4  1572864
#define N_ALL4 4718592

__device__ __forceinline__ void conv_T_body(
    const float* __restrict__ src0, short* __restrict__ dst0, int R, int C,
    int bx, int by, int bz, short (*T)[72])
{
    const int t = threadIdx.x;
    const int r0 = bx * 64, c0 = by * 64;
    const size_t bo = (size_t)bz * R * C;
    const float* src = src0 + bo;
    short* dst = dst0 + bo;
#pragma unroll
    for (int i = 0; i < 4; ++i) {
        int id = i * 256 + t;
        int r = id >> 4, c4 = id & 15;
        float4 f = *(const float4*)(src + (size_t)(r0 + r) * C + c0 + c4 * 4);
        T[c4 * 4 + 0][r] = f2bf(f.x);
        T[c4 * 4 + 1][r] = f2bf(f.y);
        T[c4 * 4 + 2][r] = f2bf(f.z);
        T[c4 * 4 + 3][r] = f2bf(f.w);
    }
    __syncthreads();
#pragma unroll
    for (int i = 0; i < 2; ++i) {
        int id = i * 256 + t;
        int cc = id >> 3, r8 = id & 7;
        *(uint4*)(dst + (size_t)(c0 + cc) * R + r0 + r8 * 8) = *(const uint4*)&T[cc][r8 * 8];
    }
}

__global__ __launch_bounds__(256) void conv_fused(
    const float* __restrict__ x, const float* __restrict__ qh,
    const float* __restrict__ kproj, const float* __restrict__ vproj,
    const float* __restrict__ lifting,
    short* __restrict__ xb, short* __restrict__ qhb,
    short* __restrict__ kTw, short* __restrict__ vTw, short* __restrict__ liftT)
{
    __shared__ short T[64][72];
    const int bid = (int)blockIdx.x;
    if (bid < CONV_STREAM_BLOCKS) {
        // grid-stride streaming convert (x then q_heads)
        for (int i = bid * 256 + (int)threadIdx.x; i < N_ALL4;
             i += CONV_STREAM_BLOCKS * 256) {
            const float4* src; ushort4* dst; int idx;
            if (i < N_X4) { src = (const float4*)x;  dst = (ushort4*)xb;  idx = i; }
            else          { src = (const float4*)qh; dst = (ushort4*)qhb; idx = i - N_X4; }
            float4 f = src[idx];
            ushort4 u;
            u.x = (unsigned short)f2bf(f.x);
            u.y = (unsigned short)f2bf(f.y);
            u.z = (unsigned short)f2bf(f.z);
            u.w = (unsigned short)f2bf(f.w);
            dst[idx] = u;
        }
    } else if (bid < CONV_STREAM_BLOCKS + 144) {
        int r = bid - CONV_STREAM_BLOCKS;          // kproj: (12 tiles, 12 heads)
        conv_T_body(kproj, kTw, E_, P_, r % 12, 0, r / 12, T);
    } else if (bid < CONV_STREAM_BLOCKS + 288) {
        int r = bid - (CONV_STREAM_BLOCKS + 144);  // vproj
        conv_T_body(vproj, vTw, E_, P_, r % 12, 0, r / 12, T);
    } else {
        int r = bid - (CONV_STREAM_BLOCKS + 288);  // lifting: (12,12)
        conv_T_body(lifting, liftT, E_, E_, r % 12, r / 12, 0, T);
    }
}

// ---------------------------------------------------------------------------
// 8-wave MFMA GEMM core: C(128x128) = A(128xK) @ [B0;B1](128xK)^T.
// T14 register-prefetch double-buffer, SCALARIZED staging state. (R9 proven)
// ---------------------------------------------------------------------------
__device__ __forceinline__ void mfma_gemm_128x128(
    const short* __restrict__ A, int lda,
    const short* __restrict__ B0, const short* __restrict__ B1, int ldb, int K,
    short (*As)[72], short (*Bs)[72], f32x4 (&acc)[2][4])
{
    const int tid = threadIdx.x;
    const int w = tid >> 6, lane = tid & 63, quad = lane >> 4, ln = lane & 15;
    const int wm = w & 3, wn = w >> 2;

    const int r = tid >> 3, c8 = (tid & 7) * 8;
    const short* sA0 = A  + (size_t)r * lda + c8;
    const short* sA1 = A  + (size_t)(r + 64) * lda + c8;
    const short* sB0 = B0 + (size_t)r * ldb + c8;
    const short* sB1 = B1 + (size_t)r * ldb + c8;
    short* dA0 = &As[r][c8];
    short* dA1 = &As[r + 64][c8];
    short* dB0 = &Bs[r][c8];
    short* dB1 = &Bs[r + 64][c8];

    // prefetch K-tile 0 into registers (scalars)
    uint4 a0p = *(const uint4*)sA0;
    uint4 a1p = *(const uint4*)sA1;
    uint4 b0p = *(const uint4*)sB0;
    uint4 b1p = *(const uint4*)sB1;

    for (int k0 = 0; k0 < K; k0 += 64) {
        __syncthreads();                    // prev compute done; LDS writable
        *(uint4*)dA0 = a0p;
        *(uint4*)dA1 = a1p;
        *(uint4*)dB0 = b0p;
        *(uint4*)dB1 = b1p;
        if (k0 + 64 < K) {                  // T14: issue next tile now
            a0p = *(const uint4*)(sA0 + k0 + 64);
            a1p = *(const uint4*)(sA1 + k0 + 64);
            b0p = *(const uint4*)(sB0 + k0 + 64);
            b1p = *(const uint4*)(sB1 + k0 + 64);
        }
        __syncthreads();                    // LDS tile ready
#pragma unroll
        for (int kc = 0; kc < 2; ++kc) {
            bf16x8 a0 = *(const bf16x8*)&As[wm * 32 + ln][kc * 32 + quad * 8];
            bf16x8 a1 = *(const bf16x8*)&As[wm * 32 + 16 + ln][kc * 32 + quad * 8];
#pragma unroll
            for (int ni = 0; ni < 4; ++ni) {
                bf16x8 b = *(const bf16x8*)&Bs[wn * 64 + ni * 16 + ln][kc * 32 + quad * 8];
                acc[0][ni] = __builtin_amdgcn_mfma_f32_16x16x32_bf16(a0, b, acc[0][ni], 0, 0, 0);
                acc[1][ni] = __builtin_amdgcn_mfma_f32_16x16x32_bf16(a1, b, acc[1][ni], 0, 0, 0);
            }
        }
    }
}

// ---------------------------------------------------------------------------
// Stage 1: one block = (m-tile, head h); computes BOTH k (wn=0) and v (wn=1).
// (512,2): reg cap 128 (this hipcc treats arg2 as min-blocks/CU for the cap;
// (512,6)->~42 regs spill, (512,4)->64, prefetch core needs ~75+).
// ---------------------------------------------------------------------------
__global__ __launch_bounds__(512, 2) void proj_kv_mfma(
    const short* __restrict__ xb,
    const short* __restrict__ kTw,   // [h][p][e] bf16
    const short* __restrict__ vTw,
    short* __restrict__ kb,          // [b][h][s][p]
    short* __restrict__ vTb)         // [b][h][p][s]
{
    __shared__ short As[128][72];
    __shared__ short Bs[128][72];
    const int tid = threadIdx.x;
    const int w = tid >> 6, lane = tid & 63, quad = lane >> 4, ln = lane & 15;
    const int wm = w & 3, wn = w >> 2;

    const int lid = (int)blockIdx.x;          // 768 blocks
    const int xcd = lid & 7, s = lid >> 3;    // s in [0,96)
    const int mloc = s & 7, h = s >> 3;       // 8 m-tiles/xcd, 12 heads
    const int m0 = (xcd * 8 + mloc) * 128;

    f32x4 acc[2][4] = {};
    mfma_gemm_128x128(xb + (size_t)m0 * E_, E_,
                      kTw + (size_t)h * P_ * E_, vTw + (size_t)h * P_ * E_, E_, E_,
                      As, Bs, acc);

    const int b = m0 >> 10;
    const int sbase = (m0 & 1023) + wm * 32;
    if (wn == 0) {
        short* outp = kb + ((size_t)(b * H_ + h)) * S_ * P_;
#pragma unroll
        for (int mi = 0; mi < 2; ++mi)
#pragma unroll
            for (int ni = 0; ni < 4; ++ni)
#pragma unroll
                for (int r = 0; r < 4; ++r) {
                    int ss = sbase + mi * 16 + quad * 4 + r;
                    outp[(size_t)ss * P_ + ni * 16 + ln] = f2bf(acc[mi][ni][r]);
                }
    } else {
        short* outp = vTb + ((size_t)(b * H_ + h)) * P_ * S_;
#pragma unroll
        for (int mi = 0; mi < 2; ++mi)
#pragma unroll
            for (int ni = 0; ni < 4; ++ni) {
                int p = ni * 16 + ln;
                int ss = sbase + mi * 16 + quad * 4;  // 4 consecutive s in regs
                ushort4 u;
                u.x = (unsigned short)f2bf(acc[mi][ni][0]);
                u.y = (unsigned short)f2bf(acc[mi][ni][1]);
                u.z = (unsigned short)f2bf(acc[mi][ni][2]);
                u.w = (unsigned short)f2bf(acc[mi][ni][3]);
                *(ushort4*)(outp + (size_t)p * S_ + ss) = u;
            }
    }
}

// ---------------------------------------------------------------------------
// Stage 2: qv[b,h] = q_heads[h] @ v[b,h]; N=128 via batch pairs.
// ---------------------------------------------------------------------------
__global__ __launch_bounds__(512, 2) void qv_mfma(
    const short* __restrict__ qhb,
    const short* __restrict__ vTb,
    short* __restrict__ qvb)
{
    __shared__ short As[128][72];
    __shared__ short Bs[128][72];
    const int tid = threadIdx.x;
    const int w = tid >> 6, lane = tid & 63, quad = lane >> 4, ln = lane & 15;
    const int wm = w & 3, wn = w >> 2;

    const int lid = (int)blockIdx.x;             // 384 blocks
    const int xcd = lid & 7, s = lid >> 3;       // s in [0,48)
    const int virt = xcd * 48 + s;               // h-major, XCD-chunked
    const int h = virt >> 5;                     // 12 heads x 32 blocks
    const int rem = virt & 31;
    const int mt = rem >> 2, bp = rem & 3;       // 8 m-tiles, 4 b-pairs
    const int m0 = mt * 128;

    const short* Bv0 = vTb + (size_t)((bp * 2 + 0) * H_ + h) * P_ * S_;
    const short* Bv1 = vTb + (size_t)((bp * 2 + 1) * H_ + h) * P_ * S_;

    f32x4 acc[2][4] = {};
    mfma_gemm_128x128(qhb + (size_t)h * S_ * S_ + (size_t)m0 * S_, S_,
                      Bv0, Bv1, S_, S_, As, Bs, acc);

    const int b = bp * 2 + wn;
    short* outp = qvb + (size_t)(b * H_ + h) * S_ * P_;
#pragma unroll
    for (int mi = 0; mi < 2; ++mi)
#pragma unroll
        for (int ni = 0; ni < 4; ++ni)
#pragma unroll
            for (int r = 0; r < 4; ++r) {
                int ss = m0 + wm * 32 + mi * 16 + quad * 4 + r;
                outp[(size_t)ss * P_ + ni * 16 + ln] = f2bf(acc[mi][ni][r]);
            }
}

// ---------------------------------------------------------------------------
// Stage 3: flash attention (R9/R12 exact: block-shared K/V reg-staging with
// T14 split, q-block pair balance, per-wave-owned outputs, no-max softmax).
// R13's async global_load_lds + raw-barrier variant killed the container
// twice -> reverted (m152-class sync risk, unverifiable headlessly).
// (512,4) proven: VGPR ~60, zero spill.
// ---------------------------------------------------------------------------
__global__ __launch_bounds__(512, 4) void flash_mfma(
    const short* __restrict__ kb,
    const short* __restrict__ qvb,
    const short* __restrict__ vTb,
    short* __restrict__ attn2)
{
    __shared__ short Ks[64][72];
    __shared__ short Vts[64][72];
    __shared__ short Ps[8][16][72];

    const int tid = threadIdx.x;
    const int w = tid >> 6, lane = tid & 63, quad = lane >> 4, ln = lane & 15;
    const int wq = w & 3;                 // 16-row strip within q-block
    const int wsel = w >> 2;              // 0 = hi q-block, 1 = lo

    const int lid = (int)blockIdx.x;      // 768 blocks, XCD-local bh
    const int xcd = lid & 7, sl = lid >> 3;
    const int bh  = xcd * 12 + (sl >> 3);
    const int pair = sl & 7;
    const int qhi = 15 - pair;
    const int qb  = wsel ? pair : qhi;
    const int b = bh / H_, h = bh % H_;

    const short* Q  = kb  + (size_t)bh * S_ * P_ + ((size_t)qb * 64 + wq * 16) * P_;
    const short* K  = qvb + (size_t)bh * S_ * P_;
    const short* Vt = vTb + (size_t)bh * P_ * S_;

    // Q fragments direct from global (one-time)
    bf16x8 qf[2];
    qf[0] = *(const bf16x8*)(Q + (size_t)ln * P_ + quad * 8);
    qf[1] = *(const bf16x8*)(Q + (size_t)ln * P_ + 32 + quad * 8);

    // staging: thread -> (row, 16B chunk); K rows stride P_, Vt rows stride S_
    const int krow = tid >> 3, kc8 = (tid & 7) * 8;
    const short* Kst = K + (size_t)krow * P_ + kc8;      // + jt*64*P_
    const short* Vst = Vt + (size_t)krow * S_ + kc8;     // + jt*64
    uint4 rK = *(const uint4*)Kst;                       // tile 0 prefetch
    uint4 rV = *(const uint4*)Vst;

    f32x4 o[4] = {};
    float l[4] = {};
    short (*Pw)[72] = Ps[w];
    const float c2 = 0.03608439182435161f * 1.4426950408889634f; // scale*log2e
    const int rowbase = wq * 16;

    for (int jt = 0; jt <= qhi; ++jt) {
        __syncthreads();                   // prev compute done; LDS writable
        *(uint4*)&Ks[krow][kc8] = rK;
        *(uint4*)&Vts[krow][kc8] = rV;
        if (jt < qhi) {                    // T14: issue next tile now
            rK = *(const uint4*)(Kst + (size_t)(jt + 1) * 64 * P_);
            rV = *(const uint4*)(Vst + (jt + 1) * 64);
        }
        __syncthreads();                   // LDS tile ready

        if (jt <= qb) {
            const bool diag = (jt == qb);
            f32x4 s[4] = {};
#pragma unroll
            for (int kc = 0; kc < 2; ++kc)
#pragma unroll
                for (int ni = 0; ni < 4; ++ni) {
                    bf16x8 kf = *(const bf16x8*)&Ks[ni * 16 + ln][kc * 32 + quad * 8];
                    s[ni] = __builtin_amdgcn_mfma_f32_16x16x32_bf16(qf[kc], kf, s[ni], 0, 0, 0);
                }

#pragma unroll
            for (int r = 0; r < 4; ++r) {
                const int row = quad * 4 + r;
                float p[4];
#pragma unroll
                for (int ni = 0; ni < 4; ++ni) {
                    float v = __builtin_amdgcn_exp2f(c2 * s[ni][r]);
                    if (diag && (ni * 16 + ln) > (rowbase + row)) v = 0.f;
                    p[ni] = v;
                    l[r] += v;
                }
#pragma unroll
                for (int ni = 0; ni < 4; ++ni)
                    Pw[row][ni * 16 + ln] = f2bf_hw(p[ni]);
            }

#pragma unroll
            for (int kc = 0; kc < 2; ++kc) {
                bf16x8 pa = *(const bf16x8*)&Pw[ln][kc * 32 + quad * 8];
#pragma unroll
                for (int ni = 0; ni < 4; ++ni) {
                    bf16x8 vb = *(const bf16x8*)&Vts[ni * 16 + ln][kc * 32 + quad * 8];
                    o[ni] = __builtin_amdgcn_mfma_f32_16x16x32_bf16(pa, vb, o[ni], 0, 0, 0);
                }
            }
        }
    }

    // epilogue: per-wave row-sum reduce + store (wave fully owns its rows)
#pragma unroll
    for (int r = 0; r < 4; ++r) {
        float lv = l[r];
#pragma unroll
        for (int off = 1; off < 16; off <<= 1)
            lv += __shfl_xor(lv, off, 16);
        float inv = 1.0f / lv;
        int gi = qb * 64 + rowbase + quad * 4 + r;
#pragma unroll
        for (int ni = 0; ni < 4; ++ni)
            attn2[((size_t)b * S_ + gi) * (H_ * P_) + h * P_ + ni * 16 + ln] =
                f2bf(o[ni][r] * inv);
    }
}

// ---------------------------------------------------------------------------
// Stage 4: out = attn2 @ lifting; N=128 via column pairs.
// ---------------------------------------------------------------------------
__global__ __launch_bounds__(512, 2) void lift_mfma(
    const short* __restrict__ attn2,
    const short* __restrict__ liftT,
    float* __restrict__ outp)
{
    __shared__ short As[128][72];
    __shared__ short Bs[128][72];
    const int tid = threadIdx.x;
    const int w = tid >> 6, lane = tid & 63, quad = lane >> 4, ln = lane & 15;
    const int wm = w & 3, wn = w >> 2;

    const int lid = (int)blockIdx.x;             // 384 blocks
    const int xcd = lid & 7, s = lid >> 3;       // s in [0,48)
    const int mloc = s & 7, np = s >> 3;         // 8 m-tiles/xcd, 6 n-pairs
    const int m0 = (xcd * 8 + mloc) * 128;
    const int n0 = np * 128;

    f32x4 acc[2][4] = {};
    mfma_gemm_128x128(attn2 + (size_t)m0 * E_, E_,
                      liftT + (size_t)n0 * E_, liftT + (size_t)(n0 + 64) * E_, E_, E_,
                      As, Bs, acc);

#pragma unroll
    for (int mi = 0; mi < 2; ++mi)
#pragma unroll
        for (int ni = 0; ni < 4; ++ni)
#pragma unroll
            for (int r = 0; r < 4; ++r) {
                int m = m0 + wm * 32 + mi * 16 + quad * 4 + r;
                outp[(size_t)m * E_ + n0 + wn * 64 + ni * 16 + ln] = acc[mi][ni][r];
            }
}

extern "C" void kernel_launch(void* const* d_in, const int* in_sizes, int n_in,
                              void* d_out, int out_size, void* d_ws, size_t ws_size,
                              hipStream_t stream) {
    (void)in_sizes; (void)n_in; (void)out_size; (void)ws_size;
    const float* x       = (const float*)d_in[0];
    const float* kproj   = (const float*)d_in[1];
    const float* vproj   = (const float*)d_in[2];
    const float* qheads  = (const float*)d_in[3];
    const float* lifting = (const float*)d_in[4];
    float* out = (float*)d_out;

    short* ws = (short*)d_ws;
    const size_t N_X   = (size_t)B_ * S_ * E_;          // 6,291,456
    const size_t N_QH  = (size_t)H_ * S_ * S_;          // 12,582,912
    const size_t N_W   = (size_t)H_ * P_ * E_;          //    589,824
    const size_t N_L   = (size_t)E_ * E_;               //    589,824
    const size_t N_KV  = (size_t)B_ * H_ * S_ * P_;     // 6,291,456

    short* xb    = ws;                 ws += N_X;
    short* qhb   = ws;                 ws += N_QH;
    short* kTw   = ws;                 ws += N_W;
    short* vTw   = ws;                 ws += N_W;
    short* liftT = ws;                 ws += N_L;
    short* kb    = ws;                 ws += N_KV;
    short* vTb   = ws;                 ws += N_KV;
    short* qvb   = ws;                 ws += N_KV;
    short* attn2 = ws;                 ws += N_KV;

    conv_fused<<<dim3(CONV_STREAM_BLOCKS + 432), 256, 0, stream>>>(
        x, qheads, kproj, vproj, lifting, xb, qhb, kTw, vTw, liftT);
    proj_kv_mfma<<<dim3(768), 512, 0, stream>>>(xb, kTw, vTw, kb, vTb);
    qv_mfma<<<dim3(384), 512, 0, stream>>>(qhb, vTb, qvb);
    flash_mfma<<<dim3(768), 512, 0, stream>>>(kb, qvb, vTb, attn2);
    lift_mfma<<<dim3(384), 512, 0, stream>>>(attn2, liftT, out);
}